// Round 4
// baseline (316.676 us; speedup 1.0000x reference)
//
#include <hip/hip_runtime.h>
#include <math.h>

#define E_TYPES 20
#define NBLK 2
#define NANG 7
#define CS 384
#define CH 128
#define N_TOK (8 * 2048)
#define TOK 16          // tokens per tile (16 -> ~1044 blocks -> 4 blocks/CU)
#define TPB 256         // threads per block, 4 waves
#define KC 128          // k-chunk for the c_s=384 input staging
#define MAX_TILES (N_TOK / TOK + E_TYPES)   // 1044
#define SROW 132        // padded LDS row stride (floats)
#define NPREP 64        // prep blocks (N_TOK / 256)

// ---- workspace layout (ints) ----
#define HIST_OFF 0           // 64 x 20 per-block histograms
#define CNT_OFF 1536         // 20 counts (published by scatter block 0)
#define POFF_OFF 1600        // 21 padded offsets (multiples of TOK)
#define PERM_OFF 2048        // padded perm entries (<= 16384 + 20*15)

// Per-block histogram -> plain stores into the 64x20 table. Every slot is
// written (zeros included) so no global zeroing pass is needed.
__global__ void hist_k(const int* __restrict__ aatype, int* ws) {
    __shared__ int lh[E_TYPES];
    int t = threadIdx.x;
    if (t < E_TYPES) lh[t] = 0;
    __syncthreads();
    int idx = blockIdx.x * blockDim.x + t;
    if (idx < N_TOK) atomicAdd(&lh[aatype[idx]], 1);
    __syncthreads();
    if (t < E_TYPES) ws[HIST_OFF + blockIdx.x * E_TYPES + t] = lh[t];
}

// Deterministic scatter: each block derives global counts, padded offsets,
// and its own per-expert base from the histogram table (no global atomics).
__global__ void scatter_k(const int* __restrict__ aatype, int* ws) {
    __shared__ int lhist[NPREP * E_TYPES];
    __shared__ int counts[E_TYPES], poff[E_TYPES + 1], mybase[E_TYPES], lcur[E_TYPES];
    int t = threadIdx.x;
    int bid = blockIdx.x;
    for (int idx = t; idx < NPREP * E_TYPES; idx += TPB)
        lhist[idx] = ws[HIST_OFF + idx];
    if (t < E_TYPES) lcur[t] = 0;
    __syncthreads();
    if (t < E_TYPES) {
        int tot = 0, pre = 0;
        for (int b = 0; b < NPREP; b++) {
            int v = lhist[b * E_TYPES + t];
            tot += v;
            if (b < bid) pre += v;
        }
        counts[t] = tot;
        mybase[t] = pre;     // within-expert offset of this block's tokens
    }
    __syncthreads();
    if (t == 0) {
        int off = 0;
        for (int e = 0; e < E_TYPES; e++) {
            poff[e] = off;
            off += (counts[e] + TOK - 1) & ~(TOK - 1);
        }
        poff[E_TYPES] = off;
    }
    __syncthreads();
    if (t < E_TYPES) mybase[t] += poff[t];
    __syncthreads();
    int idx = bid * blockDim.x + t;
    if (idx < N_TOK) {
        int e = aatype[idx];
        int r = atomicAdd(&lcur[e], 1);     // LDS-only atomic
        ws[PERM_OFF + mybase[e] + r] = idx;
    }
    if (bid == 0) {
        if (t < E_TYPES) ws[CNT_OFF + t] = counts[t];
        if (t == 0)
            for (int e = 0; e <= E_TYPES; e++) ws[POFF_OFF + e] = poff[e];
    }
}

#define LD4(dst, ptr) { float4 _v = *(const float4*)(ptr); \
    (dst)[0] = _v.x; (dst)[1] = _v.y; (dst)[2] = _v.z; (dst)[3] = _v.w; }

#define PRELOAD2(wa, wb, pA, pB, krow) { \
    wa[0] = *(const float4*)((pA) + (size_t)((krow) + 0) * CH + c0); \
    wa[1] = *(const float4*)((pA) + (size_t)((krow) + 1) * CH + c0); \
    wa[2] = *(const float4*)((pA) + (size_t)((krow) + 2) * CH + c0); \
    wa[3] = *(const float4*)((pA) + (size_t)((krow) + 3) * CH + c0); \
    wb[0] = *(const float4*)((pB) + (size_t)((krow) + 0) * CH + c0); \
    wb[1] = *(const float4*)((pB) + (size_t)((krow) + 1) * CH + c0); \
    wb[2] = *(const float4*)((pB) + (size_t)((krow) + 2) * CH + c0); \
    wb[3] = *(const float4*)((pB) + (size_t)((krow) + 3) * CH + c0); }

#define PRELOAD1(wa, pA, krow) { \
    wa[0] = *(const float4*)((pA) + (size_t)((krow) + 0) * CH + c0); \
    wa[1] = *(const float4*)((pA) + (size_t)((krow) + 1) * CH + c0); \
    wa[2] = *(const float4*)((pA) + (size_t)((krow) + 2) * CH + c0); \
    wa[3] = *(const float4*)((pA) + (size_t)((krow) + 3) * CH + c0); }

#define WF(buf, kk, cc) (((const float*)&(buf)[kk])[cc])

__global__ __launch_bounds__(TPB, 4)
void angle_main(const float* __restrict__ s, const float* __restrict__ si,
                const float* __restrict__ Win, const float* __restrict__ b_in,
                const float* __restrict__ Winit, const float* __restrict__ b_init2,
                const float* __restrict__ Wb1, const float* __restrict__ bb1,
                const float* __restrict__ Wb2, const float* __restrict__ bb2,
                const float* __restrict__ Wout, const float* __restrict__ b_out,
                const int* __restrict__ ws, float* __restrict__ out)
{
    __shared__ float smem[2][TOK][SROW];   // ~17 KB -> LDS never the limiter
    __shared__ int ptok[TOK];

    int pos = blockIdx.x * TOK;
    if (pos >= ws[POFF_OFF + E_TYPES]) return;
    int e = 0;
    while (e < E_TYPES - 1 && pos >= ws[POFF_OFF + e + 1]) e++;
    int n = ws[CNT_OFF + e] - (pos - ws[POFF_OFF + e]);
    if (n > TOK) n = TOK;   // n >= 1 by construction

    int t = threadIdx.x;
    if (t < TOK) ptok[t] = ws[PERM_OFF + pos + ((t < n) ? t : 0)];

    // wave owns a disjoint 32-channel slice; 2 tokens x 4 channels per thread
    int cgrp = (t >> 6) * 8 + (t & 7);   // 0..31
    int tgrp = (t >> 3) & 7;             // 0..7
    int c0 = 4 * cgrp;
    int tok0 = 2 * tgrp;

    __syncthreads();

    float acc[2][4];            // [token][channel]
    {
        float bi[4], b2[4];
        LD4(bi, b_in    + (size_t)e * CH + c0);
        LD4(b2, b_init2 + (size_t)e * CH + c0);
        #pragma unroll
        for (int tt = 0; tt < 2; tt++)
            #pragma unroll
            for (int cc = 0; cc < 4; cc++)
                acc[tt][cc] = bi[cc] + b2[cc];
    }

    const float* WinE   = Win   + (size_t)e * CS * CH;
    const float* WinitE = Winit + (size_t)e * CS * CH;

    float4 wa0[4], wb0[4], wa1[4], wb1[4];

    // ---- h = relu(s) @ Win + relu(s_init) @ Winit + biases ----
    for (int kc = 0; kc < CS; kc += KC) {
        __syncthreads();
        for (int idx = t; idx < TOK * (KC / 4); idx += TPB) {
            int i = idx >> 5;          // KC/4 == 32
            int c4 = idx & 31;
            float4 v = make_float4(0.f, 0.f, 0.f, 0.f);
            float4 w = make_float4(0.f, 0.f, 0.f, 0.f);
            if (i < n) {
                v = *(const float4*)(s  + (size_t)ptok[i] * CS + kc + 4 * c4);
                w = *(const float4*)(si + (size_t)ptok[i] * CS + kc + 4 * c4);
            }
            v.x = fmaxf(v.x, 0.f); v.y = fmaxf(v.y, 0.f);
            v.z = fmaxf(v.z, 0.f); v.w = fmaxf(v.w, 0.f);
            w.x = fmaxf(w.x, 0.f); w.y = fmaxf(w.y, 0.f);
            w.z = fmaxf(w.z, 0.f); w.w = fmaxf(w.w, 0.f);
            *(float4*)&smem[0][i][4 * c4] = v;
            *(float4*)&smem[1][i][4 * c4] = w;
        }
        PRELOAD2(wa0, wb0, WinE, WinitE, kc);
        __syncthreads();

        for (int k4 = 0; k4 < KC; k4 += 8) {
            PRELOAD2(wa1, wb1, WinE, WinitE, kc + k4 + 4);
            {
                float aA[2][4], aB[2][4];
                #pragma unroll
                for (int tt = 0; tt < 2; tt++) {
                    LD4(aA[tt], &smem[0][tok0 + tt][k4]);
                    LD4(aB[tt], &smem[1][tok0 + tt][k4]);
                }
                #pragma unroll
                for (int kk = 0; kk < 4; kk++)
                    #pragma unroll
                    for (int tt = 0; tt < 2; tt++)
                        #pragma unroll
                        for (int cc = 0; cc < 4; cc++)
                            acc[tt][cc] = fmaf(aA[tt][kk], WF(wa0, kk, cc),
                                          fmaf(aB[tt][kk], WF(wb0, kk, cc), acc[tt][cc]));
            }
            int kn = kc + k4 + 8;
            if (kn > CS - 4) kn = CS - 4;
            PRELOAD2(wa0, wb0, WinE, WinitE, kn);
            {
                float aA[2][4], aB[2][4];
                #pragma unroll
                for (int tt = 0; tt < 2; tt++) {
                    LD4(aA[tt], &smem[0][tok0 + tt][k4 + 4]);
                    LD4(aB[tt], &smem[1][tok0 + tt][k4 + 4]);
                }
                #pragma unroll
                for (int kk = 0; kk < 4; kk++)
                    #pragma unroll
                    for (int tt = 0; tt < 2; tt++)
                        #pragma unroll
                        for (int cc = 0; cc < 4; cc++)
                            acc[tt][cc] = fmaf(aA[tt][kk], WF(wa1, kk, cc),
                                          fmaf(aB[tt][kk], WF(wb1, kk, cc), acc[tt][cc]));
            }
        }
    }

    // ---- 2 residual blocks ----
    for (int b = 0; b < NBLK; b++) {
        const float* W1 = Wb1 + (size_t)(e * NBLK + b) * CH * CH;
        const float* W2 = Wb2 + (size_t)(e * NBLK + b) * CH * CH;

        __syncthreads();
        #pragma unroll
        for (int tt = 0; tt < 2; tt++) {
            float4 v = make_float4(fmaxf(acc[tt][0], 0.f), fmaxf(acc[tt][1], 0.f),
                                   fmaxf(acc[tt][2], 0.f), fmaxf(acc[tt][3], 0.f));
            *(float4*)&smem[0][tok0 + tt][c0] = v;
        }
        PRELOAD1(wa0, W1, 0);
        __syncthreads();

        float a2[2][4];
        {
            float bb[4];
            LD4(bb, bb1 + (size_t)(e * NBLK + b) * CH + c0);
            #pragma unroll
            for (int tt = 0; tt < 2; tt++)
                #pragma unroll
                for (int cc = 0; cc < 4; cc++) a2[tt][cc] = bb[cc];
        }
        for (int k4 = 0; k4 < CH; k4 += 8) {
            PRELOAD1(wa1, W1, k4 + 4);
            {
                float hv[2][4];
                #pragma unroll
                for (int tt = 0; tt < 2; tt++) LD4(hv[tt], &smem[0][tok0 + tt][k4]);
                #pragma unroll
                for (int kk = 0; kk < 4; kk++)
                    #pragma unroll
                    for (int tt = 0; tt < 2; tt++)
                        #pragma unroll
                        for (int cc = 0; cc < 4; cc++)
                            a2[tt][cc] = fmaf(hv[tt][kk], WF(wa0, kk, cc), a2[tt][cc]);
            }
            int kn = k4 + 8;
            if (kn > CH - 4) kn = CH - 4;
            PRELOAD1(wa0, W1, kn);
            {
                float hv[2][4];
                #pragma unroll
                for (int tt = 0; tt < 2; tt++) LD4(hv[tt], &smem[0][tok0 + tt][k4 + 4]);
                #pragma unroll
                for (int kk = 0; kk < 4; kk++)
                    #pragma unroll
                    for (int tt = 0; tt < 2; tt++)
                        #pragma unroll
                        for (int cc = 0; cc < 4; cc++)
                            a2[tt][cc] = fmaf(hv[tt][kk], WF(wa1, kk, cc), a2[tt][cc]);
            }
        }
        __syncthreads();
        #pragma unroll
        for (int tt = 0; tt < 2; tt++) {
            float4 v = make_float4(fmaxf(a2[tt][0], 0.f), fmaxf(a2[tt][1], 0.f),
                                   fmaxf(a2[tt][2], 0.f), fmaxf(a2[tt][3], 0.f));
            *(float4*)&smem[1][tok0 + tt][c0] = v;
        }
        PRELOAD1(wa0, W2, 0);
        __syncthreads();

        {
            float bb[4];
            LD4(bb, bb2 + (size_t)(e * NBLK + b) * CH + c0);
            #pragma unroll
            for (int tt = 0; tt < 2; tt++)
                #pragma unroll
                for (int cc = 0; cc < 4; cc++) a2[tt][cc] = bb[cc];
        }
        for (int k4 = 0; k4 < CH; k4 += 8) {
            PRELOAD1(wa1, W2, k4 + 4);
            {
                float av[2][4];
                #pragma unroll
                for (int tt = 0; tt < 2; tt++) LD4(av[tt], &smem[1][tok0 + tt][k4]);
                #pragma unroll
                for (int kk = 0; kk < 4; kk++)
                    #pragma unroll
                    for (int tt = 0; tt < 2; tt++)
                        #pragma unroll
                        for (int cc = 0; cc < 4; cc++)
                            a2[tt][cc] = fmaf(av[tt][kk], WF(wa0, kk, cc), a2[tt][cc]);
            }
            int kn = k4 + 8;
            if (kn > CH - 4) kn = CH - 4;
            PRELOAD1(wa0, W2, kn);
            {
                float av[2][4];
                #pragma unroll
                for (int tt = 0; tt < 2; tt++) LD4(av[tt], &smem[1][tok0 + tt][k4 + 4]);
                #pragma unroll
                for (int kk = 0; kk < 4; kk++)
                    #pragma unroll
                    for (int tt = 0; tt < 2; tt++)
                        #pragma unroll
                        for (int cc = 0; cc < 4; cc++)
                            a2[tt][cc] = fmaf(av[tt][kk], WF(wa1, kk, cc), a2[tt][cc]);
            }
        }
        #pragma unroll
        for (int tt = 0; tt < 2; tt++)
            #pragma unroll
            for (int cc = 0; cc < 4; cc++) acc[tt][cc] += a2[tt][cc];
    }

    // ---- final relu(h) -> LDS ----
    __syncthreads();
    #pragma unroll
    for (int tt = 0; tt < 2; tt++) {
        float4 v = make_float4(fmaxf(acc[tt][0], 0.f), fmaxf(acc[tt][1], 0.f),
                               fmaxf(acc[tt][2], 0.f), fmaxf(acc[tt][3], 0.f));
        *(float4*)&smem[0][tok0 + tt][c0] = v;
    }
    __syncthreads();

    // ---- out = relu(h) @ Wout + b_out (128 -> 14) ----
    const float* WoutE = Wout + (size_t)e * CH * (NANG * 2);
    const float* boutE = b_out + (size_t)e * (NANG * 2);
    for (int idx = t; idx < n * (NANG * 2); idx += TPB) {
        int i = idx / (NANG * 2);
        int o = idx % (NANG * 2);
        float v = boutE[o];
        #pragma unroll 4
        for (int k = 0; k < CH; k++)
            v = fmaf(smem[0][i][k], WoutE[(size_t)k * (NANG * 2) + o], v);
        smem[1][i][o] = v;
    }
    __syncthreads();

    // ---- pair-normalize and store ----
    for (int idx = t; idx < n * NANG; idx += TPB) {
        int i = idx / NANG;
        int a = idx % NANG;
        float x = smem[1][i][2 * a];
        float y = smem[1][i][2 * a + 1];
        float nr = fmaxf(sqrtf(x * x + y * y), 1e-12f);
        size_t base = (size_t)ptok[i] * (NANG * 2) + 2 * a;
        out[base]     = x / nr;
        out[base + 1] = y / nr;
    }
}

extern "C" void kernel_launch(void* const* d_in, const int* in_sizes, int n_in,
                              void* d_out, int out_size, void* d_ws, size_t ws_size,
                              hipStream_t stream) {
    const float* s       = (const float*)d_in[0];
    const float* s_init  = (const float*)d_in[1];
    const int*   aatype  = (const int*)d_in[2];
    const float* Win     = (const float*)d_in[3];
    const float* b_in    = (const float*)d_in[4];
    const float* Winit   = (const float*)d_in[5];
    const float* b_init2 = (const float*)d_in[6];
    const float* Wb1     = (const float*)d_in[7];
    const float* bb1     = (const float*)d_in[8];
    const float* Wb2     = (const float*)d_in[9];
    const float* bb2     = (const float*)d_in[10];
    const float* Wout    = (const float*)d_in[11];
    const float* b_out   = (const float*)d_in[12];
    int*   ws  = (int*)d_ws;
    float* out = (float*)d_out;

    hipLaunchKernelGGL(hist_k, dim3(NPREP), dim3(256), 0, stream, aatype, ws);
    hipLaunchKernelGGL(scatter_k, dim3(NPREP), dim3(TPB), 0, stream, aatype, ws);
    hipLaunchKernelGGL(angle_main, dim3(MAX_TILES), dim3(TPB), 0, stream,
                       s, s_init, Win, b_in, Winit, b_init2,
                       Wb1, bb1, Wb2, bb2, Wout, b_out, ws, out);
}

// Round 5
// 160.240 us; speedup vs baseline: 1.9763x; 1.9763x over previous
//
#include <hip/hip_runtime.h>
#include <math.h>

#define E_TYPES 20
#define NBLK 2
#define NANG 7
#define CS 384
#define CH 128
#define N_TOK (8 * 2048)
#define TOK 32
#define TPB 256
#define KC 128
#define MAX_TILES (N_TOK / TOK + E_TYPES)   // 532
#define NPREP 64

// ---- workspace: int control region ----
#define HIST_OFF 0           // 64 x 20 per-block histograms
#define CNT_OFF 1536         // 20 counts
#define POFF_OFF 1600        // 21 padded offsets (multiples of TOK)
#define PERM_OFF 2048        // padded perm entries

// ---- workspace: fragment-packed split-bf16 weights (bytes) ----
// 1KB block = 64 lanes x 16B; element (n,k): lane = (n&15)|((k>>3&3)<<4), j=k&7
#define WT1_OFF (256 * 1024)                       // phase-1 concat [768x128] per e
#define WT1_SZ  (20 * 8 * 24 * 2048)               // e x nt(8) x kb(24) x (hi1KB+lo1KB)
#define WTR_OFF (WT1_OFF + WT1_SZ)                 // residual: e x m4(4) x nt(8) x kb(4)
// total end ~13.4 MB

typedef __attribute__((ext_vector_type(8))) short bfrag;
typedef __attribute__((ext_vector_type(4))) float f32x4;

__device__ __forceinline__ void split_bf16(float x, unsigned short& h, unsigned short& l) {
    unsigned int u = __float_as_uint(x);
    unsigned int hb = (u + 0x7FFFu + ((u >> 16) & 1u)) & 0xFFFF0000u;
    h = (unsigned short)(hb >> 16);
    float r = x - __uint_as_float(hb);
    unsigned int v = __float_as_uint(r);
    l = (unsigned short)((v + 0x7FFFu + ((v >> 16) & 1u)) >> 16);
}

// prep1: blocks [0,1600) convert weights to fragment-packed split-bf16;
// blocks [1600,1664) build the per-block token histogram.
__global__ void prep1(const float* __restrict__ Win, const float* __restrict__ Winit,
                      const float* __restrict__ Wb1, const float* __restrict__ Wb2,
                      const int* __restrict__ aatype, int* __restrict__ wsI,
                      unsigned short* __restrict__ wt) {
    __shared__ int lh[E_TYPES];
    int bid = blockIdx.x;
    int t = threadIdx.x;
    if (bid >= 1600) {   // histogram part
        int b2 = bid - 1600;
        if (t < E_TYPES) lh[t] = 0;
        __syncthreads();
        int idx = b2 * 256 + t;
        if (idx < N_TOK) atomicAdd(&lh[aatype[idx]], 1);
        __syncthreads();
        if (t < E_TYPES) wsI[HIST_OFF + b2 * E_TYPES + t] = lh[t];
        return;
    }
    int gid = bid * 256 + t;
    unsigned short h[8], l[8];
    if (gid < 245760) {          // phase-1 weights: 20*8*24 blocks x 64 lanes
        int lane = gid & 63;
        int bi = gid >> 6;
        int kb = bi % 24;
        int r = bi / 24;
        int nt = r & 7, e = r >> 3;
        int n = nt * 16 + (lane & 15);
        int k0 = kb * 32 + (lane >> 4) * 8;
        #pragma unroll
        for (int j = 0; j < 8; j++) {
            int k = k0 + j;
            float x = (k < CS) ? Win[((size_t)e * CS + k) * CH + n]
                               : Winit[((size_t)e * CS + (k - CS)) * CH + n];
            split_bf16(x, h[j], l[j]);
        }
        unsigned short* dst = wt + (WT1_OFF / 2) + (size_t)bi * 1024 + lane * 8;
        *(bfrag*)dst = *(bfrag*)h;
        *(bfrag*)(dst + 512) = *(bfrag*)l;
    } else {                     // residual weights: 20*4*8*4 blocks x 64 lanes
        gid -= 245760;
        int lane = gid & 63;
        int bi = gid >> 6;       // 0..2559
        int kb = bi & 3;
        int nt = (bi >> 2) & 7;
        int m4 = (bi >> 5) & 3;
        int e = bi >> 7;
        int b = m4 >> 1;
        const float* W = (m4 & 1) ? Wb2 : Wb1;
        int n = nt * 16 + (lane & 15);
        int k0 = kb * 32 + (lane >> 4) * 8;
        #pragma unroll
        for (int j = 0; j < 8; j++) {
            int k = k0 + j;
            float x = W[(((size_t)e * NBLK + b) * CH + k) * CH + n];
            split_bf16(x, h[j], l[j]);
        }
        unsigned short* dst = wt + (WTR_OFF / 2) + (size_t)bi * 1024 + lane * 8;
        *(bfrag*)dst = *(bfrag*)h;
        *(bfrag*)(dst + 512) = *(bfrag*)l;
    }
}

// Deterministic scatter (unchanged from round 4 — verified correct).
__global__ void scatter_k(const int* __restrict__ aatype, int* ws) {
    __shared__ int lhist[NPREP * E_TYPES];
    __shared__ int counts[E_TYPES], poff[E_TYPES + 1], mybase[E_TYPES], lcur[E_TYPES];
    int t = threadIdx.x;
    int bid = blockIdx.x;
    for (int idx = t; idx < NPREP * E_TYPES; idx += TPB)
        lhist[idx] = ws[HIST_OFF + idx];
    if (t < E_TYPES) lcur[t] = 0;
    __syncthreads();
    if (t < E_TYPES) {
        int tot = 0, pre = 0;
        for (int b = 0; b < NPREP; b++) {
            int v = lhist[b * E_TYPES + t];
            tot += v;
            if (b < bid) pre += v;
        }
        counts[t] = tot;
        mybase[t] = pre;
    }
    __syncthreads();
    if (t == 0) {
        int off = 0;
        for (int e = 0; e < E_TYPES; e++) {
            poff[e] = off;
            off += (counts[e] + TOK - 1) & ~(TOK - 1);
        }
        poff[E_TYPES] = off;
    }
    __syncthreads();
    if (t < E_TYPES) mybase[t] += poff[t];
    __syncthreads();
    int idx = bid * blockDim.x + t;
    if (idx < N_TOK) {
        int e = aatype[idx];
        int r = atomicAdd(&lcur[e], 1);
        ws[PERM_OFF + mybase[e] + r] = idx;
    }
    if (bid == 0) {
        if (t < E_TYPES) ws[CNT_OFF + t] = counts[t];
        if (t == 0)
            for (int e = 0; e <= E_TYPES; e++) ws[POFF_OFF + e] = poff[e];
    }
}

#define MFMA(a, b, c) __builtin_amdgcn_mfma_f32_16x16x32_bf16((a), (b), (c), 0, 0, 0)

__global__ __launch_bounds__(TPB)
void angle_main(const float* __restrict__ s, const float* __restrict__ si,
                const float* __restrict__ b_in, const float* __restrict__ b_init2,
                const float* __restrict__ bb1, const float* __restrict__ bb2,
                const float* __restrict__ Wout, const float* __restrict__ b_out,
                const int* __restrict__ wsI, const unsigned short* __restrict__ wt,
                float* __restrict__ out)
{
    __shared__ unsigned short Ah[TOK][136];   // bf16-hi activations, padded rows
    __shared__ unsigned short Al[TOK][136];   // bf16-lo
    __shared__ float Hf[TOK][132];            // fp32 h for epilogue
    __shared__ float Of[TOK][16];
    __shared__ int ptok[TOK];

    int pos = blockIdx.x * TOK;
    if (pos >= wsI[POFF_OFF + E_TYPES]) return;
    int e = 0;
    while (e < E_TYPES - 1 && pos >= wsI[POFF_OFF + e + 1]) e++;
    int n = wsI[CNT_OFF + e] - (pos - wsI[POFF_OFF + e]);
    if (n > TOK) n = TOK;

    int t = threadIdx.x;
    if (t < TOK) ptok[t] = wsI[PERM_OFF + pos + ((t < n) ? t : 0)];

    int w = t >> 6, lane = t & 63;
    int lane15 = lane & 15, quad = lane >> 4;
    int nc[2] = { (2 * w) * 16 + lane15, (2 * w + 1) * 16 + lane15 };   // my two N cols

    const bfrag* wt1 = (const bfrag*)((const char*)wt + WT1_OFF);
    const bfrag* wtr = (const bfrag*)((const char*)wt + WTR_OFF);

    f32x4 acc[2][2];    // [m-tile][n-tile]; C layout: col=lane15, row=quad*4+reg
    {
        float bv0 = b_in[e * CH + nc[0]] + b_init2[e * CH + nc[0]];
        float bv1 = b_in[e * CH + nc[1]] + b_init2[e * CH + nc[1]];
        #pragma unroll
        for (int mt = 0; mt < 2; mt++) {
            acc[mt][0] = (f32x4){bv0, bv0, bv0, bv0};
            acc[mt][1] = (f32x4){bv1, bv1, bv1, bv1};
        }
    }

    __syncthreads();

    // ---- phase 1: h = [relu(s) relu(si)] @ [Win;Winit] + biases, K=768 ----
    int srow = t >> 3;              // staging: token row, 8 threads/row
    int scol = (t & 7) * 16;        // 16 floats per thread
    for (int c = 0; c < 6; c++) {
        const float* src = (c < 3) ? s : si;
        int kb0 = (c < 3 ? c : c - 3) * KC;
        {
            const float4* rp = (const float4*)(src + (size_t)ptok[srow] * CS + kb0 + scol);
            #pragma unroll
            for (int q = 0; q < 4; q++) {
                float4 v = rp[q];
                ushort4 hv, lv;
                split_bf16(fmaxf(v.x, 0.f), hv.x, lv.x);
                split_bf16(fmaxf(v.y, 0.f), hv.y, lv.y);
                split_bf16(fmaxf(v.z, 0.f), hv.z, lv.z);
                split_bf16(fmaxf(v.w, 0.f), hv.w, lv.w);
                *(ushort4*)&Ah[srow][scol + 4 * q] = hv;
                *(ushort4*)&Al[srow][scol + 4 * q] = lv;
            }
        }
        __syncthreads();
        #pragma unroll
        for (int ks = 0; ks < 4; ks++) {
            int kb = c * 4 + ks;
            int kl = ks * 32 + quad * 8;
            bfrag ah0 = *(const bfrag*)&Ah[lane15][kl];
            bfrag ah1 = *(const bfrag*)&Ah[16 + lane15][kl];
            bfrag al0 = *(const bfrag*)&Al[lane15][kl];
            bfrag al1 = *(const bfrag*)&Al[16 + lane15][kl];
            size_t b0 = ((size_t)(e * 8 + 2 * w) * 24 + kb) * 128;
            size_t b1 = ((size_t)(e * 8 + 2 * w + 1) * 24 + kb) * 128;
            bfrag bh0 = wt1[b0 + lane],      bl0 = wt1[b0 + 64 + lane];
            bfrag bh1 = wt1[b1 + lane],      bl1 = wt1[b1 + 64 + lane];
            acc[0][0] = MFMA(ah0, bh0, acc[0][0]);
            acc[0][0] = MFMA(ah0, bl0, acc[0][0]);
            acc[0][0] = MFMA(al0, bh0, acc[0][0]);
            acc[0][1] = MFMA(ah0, bh1, acc[0][1]);
            acc[0][1] = MFMA(ah0, bl1, acc[0][1]);
            acc[0][1] = MFMA(al0, bh1, acc[0][1]);
            acc[1][0] = MFMA(ah1, bh0, acc[1][0]);
            acc[1][0] = MFMA(ah1, bl0, acc[1][0]);
            acc[1][0] = MFMA(al1, bh0, acc[1][0]);
            acc[1][1] = MFMA(ah1, bh1, acc[1][1]);
            acc[1][1] = MFMA(ah1, bl1, acc[1][1]);
            acc[1][1] = MFMA(al1, bh1, acc[1][1]);
        }
        __syncthreads();
    }

    // ---- 2 residual blocks ----
    for (int b = 0; b < NBLK; b++) {
        // relu(h) -> split bf16 LDS (from C layout)
        #pragma unroll
        for (int mt = 0; mt < 2; mt++)
            #pragma unroll
            for (int nl = 0; nl < 2; nl++) {
                f32x4 v = acc[mt][nl];
                #pragma unroll
                for (int r = 0; r < 4; r++) {
                    int m = mt * 16 + quad * 4 + r;
                    unsigned short hh, ll;
                    split_bf16(fmaxf(v[r], 0.f), hh, ll);
                    Ah[m][nc[nl]] = hh;
                    Al[m][nc[nl]] = ll;
                }
            }
        __syncthreads();

        f32x4 a2[2][2];
        {
            float bv0 = bb1[(e * NBLK + b) * CH + nc[0]];
            float bv1 = bb1[(e * NBLK + b) * CH + nc[1]];
            #pragma unroll
            for (int mt = 0; mt < 2; mt++) {
                a2[mt][0] = (f32x4){bv0, bv0, bv0, bv0};
                a2[mt][1] = (f32x4){bv1, bv1, bv1, bv1};
            }
        }
        #pragma unroll
        for (int ks = 0; ks < 4; ks++) {
            int kl = ks * 32 + quad * 8;
            bfrag ah0 = *(const bfrag*)&Ah[lane15][kl];
            bfrag ah1 = *(const bfrag*)&Ah[16 + lane15][kl];
            bfrag al0 = *(const bfrag*)&Al[lane15][kl];
            bfrag al1 = *(const bfrag*)&Al[16 + lane15][kl];
            size_t b0 = (((size_t)(e * 4 + 2 * b) * 8 + 2 * w) * 4 + ks) * 128;
            size_t b1 = (((size_t)(e * 4 + 2 * b) * 8 + 2 * w + 1) * 4 + ks) * 128;
            bfrag bh0 = wtr[b0 + lane], bl0 = wtr[b0 + 64 + lane];
            bfrag bh1 = wtr[b1 + lane], bl1 = wtr[b1 + 64 + lane];
            a2[0][0] = MFMA(ah0, bh0, a2[0][0]);
            a2[0][0] = MFMA(ah0, bl0, a2[0][0]);
            a2[0][0] = MFMA(al0, bh0, a2[0][0]);
            a2[0][1] = MFMA(ah0, bh1, a2[0][1]);
            a2[0][1] = MFMA(ah0, bl1, a2[0][1]);
            a2[0][1] = MFMA(al0, bh1, a2[0][1]);
            a2[1][0] = MFMA(ah1, bh0, a2[1][0]);
            a2[1][0] = MFMA(ah1, bl0, a2[1][0]);
            a2[1][0] = MFMA(al1, bh0, a2[1][0]);
            a2[1][1] = MFMA(ah1, bh1, a2[1][1]);
            a2[1][1] = MFMA(ah1, bl1, a2[1][1]);
            a2[1][1] = MFMA(al1, bh1, a2[1][1]);
        }
        __syncthreads();

        // relu(a1) -> split bf16 LDS
        #pragma unroll
        for (int mt = 0; mt < 2; mt++)
            #pragma unroll
            for (int nl = 0; nl < 2; nl++) {
                f32x4 v = a2[mt][nl];
                #pragma unroll
                for (int r = 0; r < 4; r++) {
                    int m = mt * 16 + quad * 4 + r;
                    unsigned short hh, ll;
                    split_bf16(fmaxf(v[r], 0.f), hh, ll);
                    Ah[m][nc[nl]] = hh;
                    Al[m][nc[nl]] = ll;
                }
            }
        __syncthreads();

        f32x4 a3[2][2];
        {
            float bv0 = bb2[(e * NBLK + b) * CH + nc[0]];
            float bv1 = bb2[(e * NBLK + b) * CH + nc[1]];
            #pragma unroll
            for (int mt = 0; mt < 2; mt++) {
                a3[mt][0] = (f32x4){bv0, bv0, bv0, bv0};
                a3[mt][1] = (f32x4){bv1, bv1, bv1, bv1};
            }
        }
        #pragma unroll
        for (int ks = 0; ks < 4; ks++) {
            int kl = ks * 32 + quad * 8;
            bfrag ah0 = *(const bfrag*)&Ah[lane15][kl];
            bfrag ah1 = *(const bfrag*)&Ah[16 + lane15][kl];
            bfrag al0 = *(const bfrag*)&Al[lane15][kl];
            bfrag al1 = *(const bfrag*)&Al[16 + lane15][kl];
            size_t b0 = (((size_t)(e * 4 + 2 * b + 1) * 8 + 2 * w) * 4 + ks) * 128;
            size_t b1 = (((size_t)(e * 4 + 2 * b + 1) * 8 + 2 * w + 1) * 4 + ks) * 128;
            bfrag bh0 = wtr[b0 + lane], bl0 = wtr[b0 + 64 + lane];
            bfrag bh1 = wtr[b1 + lane], bl1 = wtr[b1 + 64 + lane];
            a3[0][0] = MFMA(ah0, bh0, a3[0][0]);
            a3[0][0] = MFMA(ah0, bl0, a3[0][0]);
            a3[0][0] = MFMA(al0, bh0, a3[0][0]);
            a3[0][1] = MFMA(ah0, bh1, a3[0][1]);
            a3[0][1] = MFMA(ah0, bl1, a3[0][1]);
            a3[0][1] = MFMA(al0, bh1, a3[0][1]);
            a3[1][0] = MFMA(ah1, bh0, a3[1][0]);
            a3[1][0] = MFMA(ah1, bl0, a3[1][0]);
            a3[1][0] = MFMA(al1, bh0, a3[1][0]);
            a3[1][1] = MFMA(ah1, bh1, a3[1][1]);
            a3[1][1] = MFMA(ah1, bl1, a3[1][1]);
            a3[1][1] = MFMA(al1, bh1, a3[1][1]);
        }
        #pragma unroll
        for (int mt = 0; mt < 2; mt++)
            #pragma unroll
            for (int nl = 0; nl < 2; nl++)
                acc[mt][nl] += a3[mt][nl];
        __syncthreads();
    }

    // ---- epilogue: relu(h) fp32 -> LDS ----
    #pragma unroll
    for (int mt = 0; mt < 2; mt++)
        #pragma unroll
        for (int nl = 0; nl < 2; nl++) {
            f32x4 v = acc[mt][nl];
            #pragma unroll
            for (int r = 0; r < 4; r++)
                Hf[mt * 16 + quad * 4 + r][nc[nl]] = fmaxf(v[r], 0.f);
        }
    __syncthreads();

    // ---- out = relu(h) @ Wout + b_out (128 -> 14) ----
    const float* WoutE = Wout + (size_t)e * CH * (NANG * 2);
    const float* boutE = b_out + (size_t)e * (NANG * 2);
    for (int idx = t; idx < n * (NANG * 2); idx += TPB) {
        int i = idx / (NANG * 2);
        int o = idx % (NANG * 2);
        float v = boutE[o];
        #pragma unroll 4
        for (int k = 0; k < CH; k++)
            v = fmaf(Hf[i][k], WoutE[(size_t)k * (NANG * 2) + o], v);
        Of[i][o] = v;
    }
    __syncthreads();

    // ---- pair-normalize and store ----
    for (int idx = t; idx < n * NANG; idx += TPB) {
        int i = idx / NANG;
        int a = idx % NANG;
        float x = Of[i][2 * a];
        float y = Of[i][2 * a + 1];
        float nr = fmaxf(sqrtf(x * x + y * y), 1e-12f);
        size_t base = (size_t)ptok[i] * (NANG * 2) + 2 * a;
        out[base]     = x / nr;
        out[base + 1] = y / nr;
    }
}

extern "C" void kernel_launch(void* const* d_in, const int* in_sizes, int n_in,
                              void* d_out, int out_size, void* d_ws, size_t ws_size,
                              hipStream_t stream) {
    const float* s       = (const float*)d_in[0];
    const float* s_init  = (const float*)d_in[1];
    const int*   aatype  = (const int*)d_in[2];
    const float* Win     = (const float*)d_in[3];
    const float* b_in    = (const float*)d_in[4];
    const float* Winit   = (const float*)d_in[5];
    const float* b_init2 = (const float*)d_in[6];
    const float* Wb1     = (const float*)d_in[7];
    const float* bb1     = (const float*)d_in[8];
    const float* Wb2     = (const float*)d_in[9];
    const float* bb2     = (const float*)d_in[10];
    const float* Wout    = (const float*)d_in[11];
    const float* b_out   = (const float*)d_in[12];
    int* wsI = (int*)d_ws;
    unsigned short* wt = (unsigned short*)d_ws;
    float* out = (float*)d_out;

    hipLaunchKernelGGL(prep1, dim3(1664), dim3(256), 0, stream,
                       Win, Winit, Wb1, Wb2, aatype, wsI, wt);
    hipLaunchKernelGGL(scatter_k, dim3(NPREP), dim3(TPB), 0, stream, aatype, wsI);
    hipLaunchKernelGGL(angle_main, dim3(MAX_TILES), dim3(TPB), 0, stream,
                       s, s_init, b_in, b_init2, bb1, bb2, Wout, b_out,
                       wsI, wt, out);
}